// Round 1
// baseline (1198.303 us; speedup 1.0000x reference)
//
#include <hip/hip_runtime.h>
#include <hip/hip_bf16.h>

// GCN: 3x gcn_conv + mean-pool + linear.
// out[i] = dinv[i] * (sum_{e: dst=i} g[src_e] + g[i]) + b,  g = dinv .* (x @ W)

// ---------------- CSR build ----------------

__global__ void count_indeg(const int* __restrict__ dst, int* __restrict__ indeg, int E) {
    int e = blockIdx.x * blockDim.x + threadIdx.x;
    if (e < E) atomicAdd(&indeg[dst[e]], 1);
}

__global__ __launch_bounds__(1024) void scan_dinv(const int* __restrict__ indeg,
                                                  int* __restrict__ rowptr,
                                                  int* __restrict__ cursor,
                                                  float* __restrict__ dinv, int n) {
    __shared__ int sm[1024];
    __shared__ int carry_s;
    if (threadIdx.x == 0) carry_s = 0;
    __syncthreads();
    for (int base = 0; base < n; base += 1024) {
        int i = base + (int)threadIdx.x;
        int v = (i < n) ? indeg[i] : 0;
        sm[threadIdx.x] = v;
        __syncthreads();
        #pragma unroll
        for (int off = 1; off < 1024; off <<= 1) {
            int t = (threadIdx.x >= (unsigned)off) ? sm[threadIdx.x - off] : 0;
            __syncthreads();
            sm[threadIdx.x] += t;
            __syncthreads();
        }
        int carry = carry_s;
        int incl = sm[threadIdx.x];
        if (i < n) {
            int excl = carry + incl - v;
            rowptr[i] = excl;
            cursor[i] = excl;
            dinv[i] = rsqrtf((float)v + 1.0f);  // +1 self-loop; deg >= 1 always
        }
        __syncthreads();
        if (threadIdx.x == 1023) carry_s = carry + incl;
        __syncthreads();
    }
    if (threadIdx.x == 0) rowptr[n] = carry_s;
}

__global__ void fill_csr(const int* __restrict__ src, const int* __restrict__ dst,
                         int* __restrict__ cursor, int* __restrict__ col, int E) {
    int e = blockIdx.x * blockDim.x + threadIdx.x;
    if (e < E) {
        int p = atomicAdd(&cursor[dst[e]], 1);
        col[p] = src[e];
    }
}

// ---------------- fp32 GEMM, C[m,:] = dinv[m] * (A[m,:] @ B) ----------------
// BM=BN=64, BK=16, 256 threads, 4x4 per thread.

__global__ __launch_bounds__(256) void gemm64(const float* __restrict__ A,
                                              const float* __restrict__ B,
                                              const float* __restrict__ dinv,
                                              float* __restrict__ C,
                                              int M, int N, int K) {
    __shared__ float As[16][64];
    __shared__ float Bs[16][64];
    int bm = blockIdx.x * 64;
    int bn = blockIdx.y * 64;
    int tid = threadIdx.x;
    int tx = tid & 15, ty = tid >> 4;
    float acc[4][4] = {};

    for (int k0 = 0; k0 < K; k0 += 16) {
        // A tile: 64 rows x 16 k. Each thread: one float4.
        {
            int r = tid >> 2;
            int c = (tid & 3) * 4;
            int m = bm + r;
            float4 v = make_float4(0.f, 0.f, 0.f, 0.f);
            if (m < M) v = *(const float4*)(A + (size_t)m * K + k0 + c);
            As[c + 0][r] = v.x;
            As[c + 1][r] = v.y;
            As[c + 2][r] = v.z;
            As[c + 3][r] = v.w;
            // B tile: 16 k x 64 n
            int br = tid >> 4, bc = (tid & 15) * 4;
            float4 wv = *(const float4*)(B + (size_t)(k0 + br) * N + bn + bc);
            *(float4*)&Bs[br][bc] = wv;
        }
        __syncthreads();
        #pragma unroll
        for (int k = 0; k < 16; ++k) {
            float a[4], b[4];
            *(float4*)a = *(const float4*)&As[k][ty * 4];
            *(float4*)b = *(const float4*)&Bs[k][tx * 4];
            #pragma unroll
            for (int i = 0; i < 4; ++i)
                #pragma unroll
                for (int j = 0; j < 4; ++j) acc[i][j] += a[i] * b[j];
        }
        __syncthreads();
    }
    #pragma unroll
    for (int i = 0; i < 4; ++i) {
        int m = bm + ty * 4 + i;
        if (m >= M) break;
        float s = dinv[m];
        float4 v = make_float4(acc[i][0] * s, acc[i][1] * s, acc[i][2] * s, acc[i][3] * s);
        *(float4*)(C + (size_t)m * N + bn + tx * 4) = v;
    }
}

// ---------------- aggregation: one wave per node ----------------

template <int F, bool RELU>
__global__ __launch_bounds__(256) void agg(const float* __restrict__ g,
                                           const int* __restrict__ rowptr,
                                           const int* __restrict__ col,
                                           const float* __restrict__ dinv,
                                           const float* __restrict__ bias,
                                           float* __restrict__ out, int n) {
    constexpr int VPT = F / 64;
    int wid = (int)((blockIdx.x * blockDim.x + threadIdx.x) >> 6);
    int lane = threadIdx.x & 63;
    if (wid >= n) return;
    int off = lane * VPT;
    float acc[VPT];
    #pragma unroll
    for (int j = 0; j < VPT; ++j) acc[j] = 0.f;
    int e0 = rowptr[wid], e1 = rowptr[wid + 1];
    for (int e = e0; e < e1; ++e) {
        int s = col[e];
        const float* row = g + (size_t)s * F + off;
        if constexpr (VPT == 4) {
            float4 v = *(const float4*)row;
            acc[0] += v.x; acc[1] += v.y; acc[2] += v.z; acc[3] += v.w;
        } else if constexpr (VPT == 2) {
            float2 v = *(const float2*)row;
            acc[0] += v.x; acc[1] += v.y;
        } else {
            acc[0] += row[0];
        }
    }
    const float* rowi = g + (size_t)wid * F + off;
    float di = dinv[wid];
    float res[VPT];
    #pragma unroll
    for (int j = 0; j < VPT; ++j) {
        float v = di * (acc[j] + rowi[j]) + bias[off + j];
        if (RELU) v = fmaxf(v, 0.f);
        res[j] = v;
    }
    float* orow = out + (size_t)wid * F + off;
    if constexpr (VPT == 4) {
        *(float4*)orow = make_float4(res[0], res[1], res[2], res[3]);
    } else if constexpr (VPT == 2) {
        *(float2*)orow = make_float2(res[0], res[1]);
    } else {
        orow[0] = res[0];
    }
}

// ---------------- pooling + final linear ----------------

__global__ void pool(const float* __restrict__ h, const int* __restrict__ batch,
                     float* __restrict__ sums, float* __restrict__ cnt, int n) {
    int idx = blockIdx.x * blockDim.x + threadIdx.x;
    if (idx < n * 64) {
        int i = idx >> 6, f = idx & 63;
        int b = batch[i];
        atomicAdd(&sums[b * 64 + f], h[idx]);
        if (f == 0) atomicAdd(&cnt[b], 1.0f);
    }
}

__global__ void final_lin(const float* __restrict__ sums, const float* __restrict__ cnt,
                          const float* __restrict__ Wl, const float* __restrict__ bl,
                          float* __restrict__ out) {
    int t = threadIdx.x;  // 128 threads: (graph, j)
    int g = t >> 1, j = t & 1;
    float c = fmaxf(cnt[g], 1.0f);
    float a = 0.f;
    #pragma unroll
    for (int k = 0; k < 64; ++k) a += sums[g * 64 + k] * Wl[k * 2 + j];
    out[t] = a / c + bl[j];
}

// ---------------- launch ----------------

extern "C" void kernel_launch(void* const* d_in, const int* in_sizes, int n_in,
                              void* d_out, int out_size, void* d_ws, size_t ws_size,
                              hipStream_t stream) {
    const float* x   = (const float*)d_in[0];
    const int*   ei  = (const int*)d_in[1];
    const int*   bat = (const int*)d_in[2];
    const float* W1  = (const float*)d_in[3];
    const float* b1  = (const float*)d_in[4];
    const float* W2  = (const float*)d_in[5];
    const float* b2  = (const float*)d_in[6];
    const float* W3  = (const float*)d_in[7];
    const float* b3  = (const float*)d_in[8];
    const float* Wl  = (const float*)d_in[9];
    const float* bl  = (const float*)d_in[10];
    float* out = (float*)d_out;

    const int N = in_sizes[0] / 512;
    const int E = in_sizes[1] / 2;
    const int* src = ei;
    const int* dst = ei + E;

    char* w = (char*)d_ws;
    auto alloc = [&](size_t bytes) {
        char* p = w;
        w += (bytes + 255) & ~(size_t)255;
        return p;
    };
    float* B1    = (float*)alloc((size_t)N * 256 * 4);
    float* B2    = (float*)alloc((size_t)N * 256 * 4);
    float* dinv  = (float*)alloc((size_t)N * 4);
    int* rowptr  = (int*)alloc((size_t)(N + 1) * 4);
    int* cursor  = (int*)alloc((size_t)N * 4);
    int* col     = (int*)alloc((size_t)E * 4);
    size_t zbytes = (size_t)N * 4 + 64 * 64 * 4 + 64 * 4;  // indeg + sums + cnt
    int* indeg   = (int*)alloc(zbytes);
    float* sums  = (float*)(indeg + N);
    float* cnt   = sums + 64 * 64;

    hipMemsetAsync(indeg, 0, zbytes, stream);
    count_indeg<<<(E + 255) / 256, 256, 0, stream>>>(dst, indeg, E);
    scan_dinv<<<1, 1024, 0, stream>>>(indeg, rowptr, cursor, dinv, N);
    fill_csr<<<(E + 255) / 256, 256, 0, stream>>>(src, dst, cursor, col, E);

    // layer 1: 512 -> 256
    dim3 g1((N + 63) / 64, 256 / 64);
    gemm64<<<g1, 256, 0, stream>>>(x, W1, dinv, B1, N, 256, 512);
    agg<256, true><<<(N + 3) / 4, 256, 0, stream>>>(B1, rowptr, col, dinv, b1, B2, N);
    // layer 2: 256 -> 128
    dim3 g2((N + 63) / 64, 128 / 64);
    gemm64<<<g2, 256, 0, stream>>>(B2, W2, dinv, B1, N, 128, 256);
    agg<128, true><<<(N + 3) / 4, 256, 0, stream>>>(B1, rowptr, col, dinv, b2, B2, N);
    // layer 3: 128 -> 64
    dim3 g3((N + 63) / 64, 1);
    gemm64<<<g3, 256, 0, stream>>>(B2, W3, dinv, B1, N, 64, 128);
    agg<64, false><<<(N + 3) / 4, 256, 0, stream>>>(B1, rowptr, col, dinv, b3, B2, N);

    pool<<<((N * 64) + 255) / 256, 256, 0, stream>>>(B2, bat, sums, cnt, N);
    final_lin<<<1, 128, 0, stream>>>(sums, cnt, Wl, bl, out);
}

// Round 2
// 874.902 us; speedup vs baseline: 1.3696x; 1.3696x over previous
//
#include <hip/hip_runtime.h>
#include <hip/hip_bf16.h>

// GCN: 3x gcn_conv + mean-pool + linear.
// out[i] = dinv[i] * (sum_{e: dst=i} g[src_e] + g[i]) + b,  g = dinv .* (x @ W)

// ---------------- CSR build ----------------

__global__ void count_indeg(const int* __restrict__ dst, int* __restrict__ indeg, int E) {
    int e = blockIdx.x * blockDim.x + threadIdx.x;
    if (e < E) atomicAdd(&indeg[dst[e]], 1);
}

__global__ __launch_bounds__(1024) void scan_dinv(const int* __restrict__ indeg,
                                                  int* __restrict__ rowptr,
                                                  int* __restrict__ cursor,
                                                  float* __restrict__ dinv, int n) {
    __shared__ int sm[1024];
    __shared__ int carry_s;
    if (threadIdx.x == 0) carry_s = 0;
    __syncthreads();
    for (int base = 0; base < n; base += 1024) {
        int i = base + (int)threadIdx.x;
        int v = (i < n) ? indeg[i] : 0;
        sm[threadIdx.x] = v;
        __syncthreads();
        #pragma unroll
        for (int off = 1; off < 1024; off <<= 1) {
            int t = (threadIdx.x >= (unsigned)off) ? sm[threadIdx.x - off] : 0;
            __syncthreads();
            sm[threadIdx.x] += t;
            __syncthreads();
        }
        int carry = carry_s;
        int incl = sm[threadIdx.x];
        if (i < n) {
            int excl = carry + incl - v;
            rowptr[i] = excl;
            cursor[i] = excl;
            dinv[i] = rsqrtf((float)v + 1.0f);  // +1 self-loop; deg >= 1 always
        }
        __syncthreads();
        if (threadIdx.x == 1023) carry_s = carry + incl;
        __syncthreads();
    }
    if (threadIdx.x == 0) rowptr[n] = carry_s;
}

__global__ void fill_csr(const int* __restrict__ src, const int* __restrict__ dst,
                         int* __restrict__ cursor, int* __restrict__ col, int E) {
    int e = blockIdx.x * blockDim.x + threadIdx.x;
    if (e < E) {
        int p = atomicAdd(&cursor[dst[e]], 1);
        col[p] = src[e];
    }
}

// ---------------- fp32 GEMM, C[m,:] = dinv[m] * (A[m,:] @ B) ----------------
// BM=BN=64, BK=16, 256 threads, 4x4 per thread.

__global__ __launch_bounds__(256) void gemm64(const float* __restrict__ A,
                                              const float* __restrict__ B,
                                              const float* __restrict__ dinv,
                                              float* __restrict__ C,
                                              int M, int N, int K) {
    __shared__ float As[16][64];
    __shared__ float Bs[16][64];
    int bm = blockIdx.x * 64;
    int bn = blockIdx.y * 64;
    int tid = threadIdx.x;
    int tx = tid & 15, ty = tid >> 4;
    float acc[4][4] = {};

    for (int k0 = 0; k0 < K; k0 += 16) {
        // A tile: 64 rows x 16 k. Each thread: one float4.
        {
            int r = tid >> 2;
            int c = (tid & 3) * 4;
            int m = bm + r;
            float4 v = make_float4(0.f, 0.f, 0.f, 0.f);
            if (m < M) v = *(const float4*)(A + (size_t)m * K + k0 + c);
            As[c + 0][r] = v.x;
            As[c + 1][r] = v.y;
            As[c + 2][r] = v.z;
            As[c + 3][r] = v.w;
            // B tile: 16 k x 64 n
            int br = tid >> 4, bc = (tid & 15) * 4;
            float4 wv = *(const float4*)(B + (size_t)(k0 + br) * N + bn + bc);
            *(float4*)&Bs[br][bc] = wv;
        }
        __syncthreads();
        #pragma unroll
        for (int k = 0; k < 16; ++k) {
            float a[4], b[4];
            *(float4*)a = *(const float4*)&As[k][ty * 4];
            *(float4*)b = *(const float4*)&Bs[k][tx * 4];
            #pragma unroll
            for (int i = 0; i < 4; ++i)
                #pragma unroll
                for (int j = 0; j < 4; ++j) acc[i][j] += a[i] * b[j];
        }
        __syncthreads();
    }
    #pragma unroll
    for (int i = 0; i < 4; ++i) {
        int m = bm + ty * 4 + i;
        if (m >= M) break;
        float s = dinv[m];
        float4 v = make_float4(acc[i][0] * s, acc[i][1] * s, acc[i][2] * s, acc[i][3] * s);
        *(float4*)(C + (size_t)m * N + bn + tx * 4) = v;
    }
}

// ---------------- aggregation: one wave per node ----------------

template <int F, bool RELU>
__global__ __launch_bounds__(256) void agg(const float* __restrict__ g,
                                           const int* __restrict__ rowptr,
                                           const int* __restrict__ col,
                                           const float* __restrict__ dinv,
                                           const float* __restrict__ bias,
                                           float* __restrict__ out, int n) {
    constexpr int VPT = F / 64;
    int wid = (int)((blockIdx.x * blockDim.x + threadIdx.x) >> 6);
    int lane = threadIdx.x & 63;
    if (wid >= n) return;
    int off = lane * VPT;
    float acc[VPT];
    #pragma unroll
    for (int j = 0; j < VPT; ++j) acc[j] = 0.f;
    int e0 = rowptr[wid], e1 = rowptr[wid + 1];
    for (int e = e0; e < e1; ++e) {
        int s = col[e];
        const float* row = g + (size_t)s * F + off;
        if constexpr (VPT == 4) {
            float4 v = *(const float4*)row;
            acc[0] += v.x; acc[1] += v.y; acc[2] += v.z; acc[3] += v.w;
        } else if constexpr (VPT == 2) {
            float2 v = *(const float2*)row;
            acc[0] += v.x; acc[1] += v.y;
        } else {
            acc[0] += row[0];
        }
    }
    const float* rowi = g + (size_t)wid * F + off;
    float di = dinv[wid];
    float res[VPT];
    #pragma unroll
    for (int j = 0; j < VPT; ++j) {
        float v = di * (acc[j] + rowi[j]) + bias[off + j];
        if (RELU) v = fmaxf(v, 0.f);
        res[j] = v;
    }
    float* orow = out + (size_t)wid * F + off;
    if constexpr (VPT == 4) {
        *(float4*)orow = make_float4(res[0], res[1], res[2], res[3]);
    } else if constexpr (VPT == 2) {
        *(float2*)orow = make_float2(res[0], res[1]);
    } else {
        orow[0] = res[0];
    }
}

// ---------------- pooling + final linear ----------------
// batch is SORTED: run-length reduce per wave, flush one atomic per (run, lane).

__global__ __launch_bounds__(256) void pool_sorted(const float* __restrict__ h,
                                                   const int* __restrict__ batch,
                                                   float* __restrict__ sums,
                                                   float* __restrict__ cnt, int n) {
    int wave = (int)((blockIdx.x * blockDim.x + threadIdx.x) >> 6);
    int lane = threadIdx.x & 63;
    int start = wave * 64;
    if (start >= n) return;
    int end = min(start + 64, n);
    float acc = 0.f;
    int cur = batch[start];
    int runlen = 0;
    for (int i = start; i < end; ++i) {
        int b = batch[i];
        if (b != cur) {
            atomicAdd(&sums[cur * 64 + lane], acc);
            if (lane == 0) atomicAdd(&cnt[cur], (float)runlen);
            acc = 0.f;
            runlen = 0;
            cur = b;
        }
        acc += h[(size_t)i * 64 + lane];
        runlen++;
    }
    atomicAdd(&sums[cur * 64 + lane], acc);
    if (lane == 0) atomicAdd(&cnt[cur], (float)runlen);
}

__global__ void final_lin(const float* __restrict__ sums, const float* __restrict__ cnt,
                          const float* __restrict__ Wl, const float* __restrict__ bl,
                          float* __restrict__ out) {
    int t = threadIdx.x;  // 128 threads: (graph, j)
    int g = t >> 1, j = t & 1;
    float c = fmaxf(cnt[g], 1.0f);
    float a = 0.f;
    #pragma unroll
    for (int k = 0; k < 64; ++k) a += sums[g * 64 + k] * Wl[k * 2 + j];
    out[t] = a / c + bl[j];
}

// ---------------- launch ----------------

extern "C" void kernel_launch(void* const* d_in, const int* in_sizes, int n_in,
                              void* d_out, int out_size, void* d_ws, size_t ws_size,
                              hipStream_t stream) {
    const float* x   = (const float*)d_in[0];
    const int*   ei  = (const int*)d_in[1];
    const int*   bat = (const int*)d_in[2];
    const float* W1  = (const float*)d_in[3];
    const float* b1  = (const float*)d_in[4];
    const float* W2  = (const float*)d_in[5];
    const float* b2  = (const float*)d_in[6];
    const float* W3  = (const float*)d_in[7];
    const float* b3  = (const float*)d_in[8];
    const float* Wl  = (const float*)d_in[9];
    const float* bl  = (const float*)d_in[10];
    float* out = (float*)d_out;

    const int N = in_sizes[0] / 512;
    const int E = in_sizes[1] / 2;
    const int* src = ei;
    const int* dst = ei + E;

    char* w = (char*)d_ws;
    auto alloc = [&](size_t bytes) {
        char* p = w;
        w += (bytes + 255) & ~(size_t)255;
        return p;
    };
    float* B1    = (float*)alloc((size_t)N * 256 * 4);
    float* B2    = (float*)alloc((size_t)N * 256 * 4);
    float* dinv  = (float*)alloc((size_t)N * 4);
    int* rowptr  = (int*)alloc((size_t)(N + 1) * 4);
    int* cursor  = (int*)alloc((size_t)N * 4);
    int* col     = (int*)alloc((size_t)E * 4);
    size_t zbytes = (size_t)N * 4 + 64 * 64 * 4 + 64 * 4;  // indeg + sums + cnt
    int* indeg   = (int*)alloc(zbytes);
    float* sums  = (float*)(indeg + N);
    float* cnt   = sums + 64 * 64;

    hipMemsetAsync(indeg, 0, zbytes, stream);
    count_indeg<<<(E + 255) / 256, 256, 0, stream>>>(dst, indeg, E);
    scan_dinv<<<1, 1024, 0, stream>>>(indeg, rowptr, cursor, dinv, N);
    fill_csr<<<(E + 255) / 256, 256, 0, stream>>>(src, dst, cursor, col, E);

    // layer 1: 512 -> 256
    dim3 g1((N + 63) / 64, 256 / 64);
    gemm64<<<g1, 256, 0, stream>>>(x, W1, dinv, B1, N, 256, 512);
    agg<256, true><<<(N + 3) / 4, 256, 0, stream>>>(B1, rowptr, col, dinv, b1, B2, N);
    // layer 2: 256 -> 128
    dim3 g2((N + 63) / 64, 128 / 64);
    gemm64<<<g2, 256, 0, stream>>>(B2, W2, dinv, B1, N, 128, 256);
    agg<128, true><<<(N + 3) / 4, 256, 0, stream>>>(B1, rowptr, col, dinv, b2, B2, N);
    // layer 3: 128 -> 64
    dim3 g3((N + 63) / 64, 1);
    gemm64<<<g3, 256, 0, stream>>>(B2, W3, dinv, B1, N, 64, 128);
    agg<64, false><<<(N + 3) / 4, 256, 0, stream>>>(B1, rowptr, col, dinv, b3, B2, N);

    // pooling: one wave per 64 consecutive (sorted-by-batch) nodes
    pool_sorted<<<(N + 255) / 256, 256, 0, stream>>>(B2, bat, sums, cnt, N);
    final_lin<<<1, 128, 0, stream>>>(sums, cnt, Wl, bl, out);
}

// Round 3
// 627.905 us; speedup vs baseline: 1.9084x; 1.3934x over previous
//
#include <hip/hip_runtime.h>
#include <hip/hip_bf16.h>

// GCN: 3x gcn_conv + mean-pool + linear, bf16 MFMA pipeline.
// out[i] = dinv[i] * (sum_{e: dst=i} g[src_e] + g[i]) + b,  g = dinv .* (x @ W)

typedef __attribute__((ext_vector_type(8))) short short8_t;
typedef __attribute__((ext_vector_type(4))) float float4_t;

__device__ __forceinline__ unsigned short f2bf(float f) {
    unsigned int u = __float_as_uint(f);
    u += 0x7FFFu + ((u >> 16) & 1u);   // round-to-nearest-even
    return (unsigned short)(u >> 16);
}
__device__ __forceinline__ float bf2f(unsigned short h) {
    return __uint_as_float(((unsigned int)h) << 16);
}

// ---------------- converts ----------------

__global__ __launch_bounds__(256) void conv_x_k(const float* __restrict__ x,
                                                ushort* __restrict__ Xb,
                                                int M, int Mpad) {
    int t = blockIdx.x * 256 + threadIdx.x;  // one float4 -> ushort4
    int total = Mpad * 128;                  // 512/4 per row
    if (t >= total) return;
    int row = t >> 7;
    ushort4 o;
    if (row < M) {
        float4 v = ((const float4*)x)[t];
        o.x = f2bf(v.x); o.y = f2bf(v.y); o.z = f2bf(v.z); o.w = f2bf(v.w);
    } else {
        o.x = o.y = o.z = o.w = 0;
    }
    ((ushort4*)Xb)[t] = o;
}

// W fp32 [K][N] -> Wt bf16 [Npad][K] (transposed, zero-padded rows)
__global__ void conv_wt_k(const float* __restrict__ W, ushort* __restrict__ Wt,
                          int kshift, int N, int total) {
    int t = blockIdx.x * 256 + threadIdx.x;
    if (t >= total) return;
    int K = 1 << kshift;
    int n = t >> kshift, k = t & (K - 1);
    Wt[t] = (n < N) ? f2bf(W[(size_t)k * N + n]) : (ushort)0;
}

// ---------------- CSR build ----------------

__global__ void count_indeg(const int* __restrict__ dst, int* __restrict__ indeg, int E) {
    int e = blockIdx.x * blockDim.x + threadIdx.x;
    if (e < E) atomicAdd(&indeg[dst[e]], 1);
}

// hierarchical scan: per-1024-chunk inclusive -> chunk totals -> combine
__global__ __launch_bounds__(1024) void scan1(const int* __restrict__ indeg,
                                              int* __restrict__ incl,   // rowptr as temp
                                              int* __restrict__ part, int n) {
    __shared__ int sm[1024];
    int i = blockIdx.x * 1024 + threadIdx.x;
    int v = (i < n) ? indeg[i] : 0;
    sm[threadIdx.x] = v;
    __syncthreads();
    #pragma unroll
    for (int off = 1; off < 1024; off <<= 1) {
        int t = (threadIdx.x >= (unsigned)off) ? sm[threadIdx.x - off] : 0;
        __syncthreads();
        sm[threadIdx.x] += t;
        __syncthreads();
    }
    if (i < n) incl[i] = sm[threadIdx.x];
    if (threadIdx.x == 1023) part[blockIdx.x] = sm[1023];
}

__global__ void scan2(int* __restrict__ part, int nb) {
    int t = threadIdx.x;  // 64
    int v = (t < nb) ? part[t] : 0;
    int orig = v;
    #pragma unroll
    for (int off = 1; off < 64; off <<= 1) {
        int u = __shfl_up(v, off, 64);
        if (t >= off) v += u;
    }
    if (t < nb) part[t] = v - orig;  // exclusive chunk offset
}

__global__ void scan3(const int* __restrict__ indeg, int* __restrict__ rowptr,
                      int* __restrict__ cursor, const int* __restrict__ part,
                      float* __restrict__ dinv, int n, int E) {
    int i = blockIdx.x * blockDim.x + threadIdx.x;
    if (i < n) {
        int excl = rowptr[i] - indeg[i] + part[i >> 10];
        rowptr[i] = excl;
        cursor[i] = excl;
        dinv[i] = rsqrtf((float)indeg[i] + 1.0f);  // +1 self-loop
    }
    if (i == 0) rowptr[n] = E;
}

__global__ void fill_csr(const int* __restrict__ src, const int* __restrict__ dst,
                         int* __restrict__ cursor, int* __restrict__ col, int E) {
    int e = blockIdx.x * blockDim.x + threadIdx.x;
    if (e < E) {
        int p = atomicAdd(&cursor[dst[e]], 1);
        col[p] = src[e];
    }
}

// ---------------- bf16 MFMA GEMM: C[m,n] = dinv[m] * sum_k A[m,k]*Bt[n,k] ----------------
// 128x128 tile, 256 threads = 4 waves (2x2), each wave 4x4 tiles of 16x16x32.

__global__ __launch_bounds__(256) void gemm_mfma(const ushort* __restrict__ A,
                                                 const ushort* __restrict__ Bt,
                                                 const float* __restrict__ dinv,
                                                 ushort* __restrict__ C,
                                                 int M, int Ncols, int K, int ldc) {
    __shared__ __align__(16) ushort As[128 * 32];
    __shared__ __align__(16) ushort Bs[128 * 32];
    int tid = threadIdx.x;
    int lane = tid & 63, w = tid >> 6;
    int wr = w >> 1, wc = w & 1;
    int bm = blockIdx.x * 128, bn = blockIdx.y * 128;

    float4_t acc[4][4];
    #pragma unroll
    for (int i = 0; i < 4; ++i)
        #pragma unroll
        for (int j = 0; j < 4; ++j) acc[i][j] = (float4_t)0.0f;

    // staging: thread t handles 16 B; rows 0..63 (issue 0) / 64..127 (issue 1)
    int r0 = tid >> 2;
    int kb = (tid & 3) * 8;  // element offset in 32-wide k-tile
    const ushort* ga0 = A + (size_t)(bm + r0) * K + kb;
    const ushort* ga1 = A + (size_t)(bm + r0 + 64) * K + kb;
    const ushort* gb0 = Bt + (size_t)(bn + r0) * K + kb;
    const ushort* gb1 = Bt + (size_t)(bn + r0 + 64) * K + kb;
    int ldsoff = r0 * 32 + kb;

    int arow = wr * 64 + (lane & 15);
    int brow = wc * 64 + (lane & 15);
    int quad = lane >> 4;

    for (int k0 = 0; k0 < K; k0 += 32) {
        short8_t a0 = *(const short8_t*)(ga0 + k0);
        short8_t a1 = *(const short8_t*)(ga1 + k0);
        short8_t b0 = *(const short8_t*)(gb0 + k0);
        short8_t b1 = *(const short8_t*)(gb1 + k0);
        __syncthreads();  // previous iter's readers done
        *(short8_t*)&As[ldsoff]        = a0;
        *(short8_t*)&As[ldsoff + 2048] = a1;
        *(short8_t*)&Bs[ldsoff]        = b0;
        *(short8_t*)&Bs[ldsoff + 2048] = b1;
        __syncthreads();
        short8_t aF[4], bF[4];
        #pragma unroll
        for (int i = 0; i < 4; ++i)
            aF[i] = *(const short8_t*)&As[(arow + i * 16) * 32 + quad * 8];
        #pragma unroll
        for (int j = 0; j < 4; ++j)
            bF[j] = *(const short8_t*)&Bs[(brow + j * 16) * 32 + quad * 8];
        #pragma unroll
        for (int i = 0; i < 4; ++i)
            #pragma unroll
            for (int j = 0; j < 4; ++j)
                acc[i][j] = __builtin_amdgcn_mfma_f32_16x16x32_bf16(aF[i], bF[j], acc[i][j], 0, 0, 0);
    }

    // C/D layout: col = lane&15, row = (lane>>4)*4 + reg
    int colb = bn + wc * 64 + (lane & 15);
    #pragma unroll
    for (int i = 0; i < 4; ++i) {
        int mb = bm + wr * 64 + i * 16 + quad * 4;
        #pragma unroll
        for (int r = 0; r < 4; ++r) {
            int m = mb + r;
            if (m >= M) continue;
            float s = dinv[m];
            #pragma unroll
            for (int j = 0; j < 4; ++j) {
                int n = colb + j * 16;
                if (n < Ncols) C[(size_t)m * ldc + n] = f2bf(acc[i][j][r] * s);
            }
        }
    }
}

// ---------------- aggregation: one wave per node, bf16 in/out ----------------

template <int F, bool RELU>
__global__ __launch_bounds__(256) void agg_bf(const ushort* __restrict__ g,
                                              const int* __restrict__ rowptr,
                                              const int* __restrict__ col,
                                              const float* __restrict__ dinv,
                                              const float* __restrict__ bias,
                                              ushort* __restrict__ out,
                                              int n, int npad) {
    constexpr int VPT = F / 64;
    int wid = (int)((blockIdx.x * blockDim.x + threadIdx.x) >> 6);
    int lane = threadIdx.x & 63;
    if (wid >= npad) return;
    int off = lane * VPT;
    ushort* orow = out + (size_t)wid * F + off;
    if (wid >= n) {  // zero padded tail rows (next GEMM reads them)
        #pragma unroll
        for (int j = 0; j < VPT; ++j) orow[j] = 0;
        return;
    }
    float acc[VPT];
    #pragma unroll
    for (int j = 0; j < VPT; ++j) acc[j] = 0.f;
    int e0 = rowptr[wid], e1 = rowptr[wid + 1];
    for (int e = e0; e < e1; ++e) {
        int s = col[e];
        const ushort* row = g + (size_t)s * F + off;
        if constexpr (VPT == 4) {
            ushort4 v = *(const ushort4*)row;
            acc[0] += bf2f(v.x); acc[1] += bf2f(v.y); acc[2] += bf2f(v.z); acc[3] += bf2f(v.w);
        } else if constexpr (VPT == 2) {
            ushort2 v = *(const ushort2*)row;
            acc[0] += bf2f(v.x); acc[1] += bf2f(v.y);
        } else {
            acc[0] += bf2f(row[0]);
        }
    }
    const ushort* rowi = g + (size_t)wid * F + off;
    float di = dinv[wid];
    #pragma unroll
    for (int j = 0; j < VPT; ++j) {
        float v = di * (acc[j] + bf2f(rowi[j])) + bias[off + j];
        if (RELU) v = fmaxf(v, 0.f);
        orow[j] = f2bf(v);
    }
}

// ---------------- pooling + final linear ----------------

__global__ __launch_bounds__(256) void pool_sorted(const ushort* __restrict__ h,
                                                   const int* __restrict__ batch,
                                                   float* __restrict__ sums,
                                                   float* __restrict__ cnt, int n) {
    int wave = (int)((blockIdx.x * blockDim.x + threadIdx.x) >> 6);
    int lane = threadIdx.x & 63;
    int start = wave * 64;
    if (start >= n) return;
    int end = min(start + 64, n);
    float acc = 0.f;
    int cur = batch[start];
    int runlen = 0;
    for (int i = start; i < end; ++i) {
        int b = batch[i];
        if (b != cur) {
            atomicAdd(&sums[cur * 64 + lane], acc);
            if (lane == 0) atomicAdd(&cnt[cur], (float)runlen);
            acc = 0.f;
            runlen = 0;
            cur = b;
        }
        acc += bf2f(h[(size_t)i * 64 + lane]);
        runlen++;
    }
    atomicAdd(&sums[cur * 64 + lane], acc);
    if (lane == 0) atomicAdd(&cnt[cur], (float)runlen);
}

__global__ void final_lin(const float* __restrict__ sums, const float* __restrict__ cnt,
                          const float* __restrict__ Wl, const float* __restrict__ bl,
                          float* __restrict__ out) {
    int t = threadIdx.x;  // 128 threads: (graph, j)
    int g = t >> 1, j = t & 1;
    float c = fmaxf(cnt[g], 1.0f);
    float a = 0.f;
    #pragma unroll
    for (int k = 0; k < 64; ++k) a += sums[g * 64 + k] * Wl[k * 2 + j];
    out[t] = a / c + bl[j];
}

// ---------------- launch ----------------

extern "C" void kernel_launch(void* const* d_in, const int* in_sizes, int n_in,
                              void* d_out, int out_size, void* d_ws, size_t ws_size,
                              hipStream_t stream) {
    const float* x   = (const float*)d_in[0];
    const int*   ei  = (const int*)d_in[1];
    const int*   bat = (const int*)d_in[2];
    const float* W1  = (const float*)d_in[3];
    const float* b1  = (const float*)d_in[4];
    const float* W2  = (const float*)d_in[5];
    const float* b2  = (const float*)d_in[6];
    const float* W3  = (const float*)d_in[7];
    const float* b3  = (const float*)d_in[8];
    const float* Wl  = (const float*)d_in[9];
    const float* bl  = (const float*)d_in[10];
    float* out = (float*)d_out;

    const int N = in_sizes[0] / 512;
    const int E = in_sizes[1] / 2;
    const int Mpad = ((N + 127) / 128) * 128;   // 50048
    const int* src = ei;
    const int* dst = ei + E;

    char* w = (char*)d_ws;
    auto alloc = [&](size_t bytes) {
        char* p = w;
        w += (bytes + 255) & ~(size_t)255;
        return p;
    };
    ushort* Xb   = (ushort*)alloc((size_t)Mpad * 512 * 2);  // layer-1 A; H aliases it later
    ushort* G    = (ushort*)alloc((size_t)Mpad * 256 * 2);  // gemm output
    ushort* Wt1  = (ushort*)alloc(256 * 512 * 2);
    ushort* Wt2  = (ushort*)alloc(128 * 256 * 2);
    ushort* Wt3  = (ushort*)alloc(128 * 128 * 2);
    float* dinv  = (float*)alloc((size_t)N * 4);
    int* rowptr  = (int*)alloc((size_t)(N + 1) * 4);
    int* cursor  = (int*)alloc((size_t)N * 4);
    int* col     = (int*)alloc((size_t)E * 4);
    int* part    = (int*)alloc(256 * 4);
    size_t zbytes = (size_t)N * 4 + 64 * 64 * 4 + 64 * 4;  // indeg + sums + cnt
    int* indeg   = (int*)alloc(zbytes);
    float* sums  = (float*)(indeg + N);
    float* cnt   = sums + 64 * 64;
    ushort* H    = Xb;  // alias: Xb dead after gemm L1; H is Mpad*256 bf16 max

    hipMemsetAsync(indeg, 0, zbytes, stream);

    // converts
    conv_x_k<<<(Mpad * 128 + 255) / 256, 256, 0, stream>>>(x, Xb, N, Mpad);
    conv_wt_k<<<(256 * 512 + 255) / 256, 256, 0, stream>>>(W1, Wt1, 9, 256, 256 * 512);
    conv_wt_k<<<(128 * 256 + 255) / 256, 256, 0, stream>>>(W2, Wt2, 8, 128, 128 * 256);
    conv_wt_k<<<(128 * 128 + 255) / 256, 256, 0, stream>>>(W3, Wt3, 7, 64, 128 * 128);

    // CSR
    count_indeg<<<(E + 255) / 256, 256, 0, stream>>>(dst, indeg, E);
    int nb = (N + 1023) / 1024;
    scan1<<<nb, 1024, 0, stream>>>(indeg, rowptr, part, N);
    scan2<<<1, 64, 0, stream>>>(part, nb);
    scan3<<<(N + 255) / 256, 256, 0, stream>>>(indeg, rowptr, cursor, part, dinv, N, E);
    fill_csr<<<(E + 255) / 256, 256, 0, stream>>>(src, dst, cursor, col, E);

    int npad = Mpad;
    dim3 gemm_block(256);
    // layer 1: 512 -> 256
    gemm_mfma<<<dim3(Mpad / 128, 2), gemm_block, 0, stream>>>(Xb, Wt1, dinv, G, N, 256, 512, 256);
    agg_bf<256, true><<<npad / 4, 256, 0, stream>>>(G, rowptr, col, dinv, b1, H, N, npad);
    // layer 2: 256 -> 128
    gemm_mfma<<<dim3(Mpad / 128, 1), gemm_block, 0, stream>>>(H, Wt2, dinv, G, N, 128, 256, 128);
    agg_bf<128, true><<<npad / 4, 256, 0, stream>>>(G, rowptr, col, dinv, b2, H, N, npad);
    // layer 3: 128 -> 64 (Wt3 padded to 128 rows, store guarded n<64)
    gemm_mfma<<<dim3(Mpad / 128, 1), gemm_block, 0, stream>>>(H, Wt3, dinv, G, N, 64, 128, 64);
    agg_bf<64, false><<<npad / 4, 256, 0, stream>>>(G, rowptr, col, dinv, b3, H, N, npad);

    pool_sorted<<<(N + 255) / 256, 256, 0, stream>>>(H, bat, sums, cnt, N);
    final_lin<<<1, 128, 0, stream>>>(sums, cnt, Wl, bl, out);
}

// Round 4
// 497.717 us; speedup vs baseline: 2.4076x; 1.2616x over previous
//
#include <hip/hip_runtime.h>
#include <hip/hip_bf16.h>

// GCN: 3x gcn_conv + mean-pool + linear, bf16 MFMA pipeline.
// out[i] = dinv[i] * (sum_{e: dst=i} g[src_e] + g[i]) + b,  g = dinv .* (x @ W)

typedef __attribute__((ext_vector_type(8))) short short8_t;
typedef __attribute__((ext_vector_type(4))) float float4_t;

__device__ __forceinline__ unsigned short f2bf(float f) {
    unsigned int u = __float_as_uint(f);
    u += 0x7FFFu + ((u >> 16) & 1u);   // round-to-nearest-even
    return (unsigned short)(u >> 16);
}
__device__ __forceinline__ float bf2f(unsigned short h) {
    return __uint_as_float(((unsigned int)h) << 16);
}

// ---------------- converts ----------------

__global__ __launch_bounds__(256) void conv_x_k(const float* __restrict__ x,
                                                ushort* __restrict__ Xb,
                                                int M, int Mpad) {
    int t = blockIdx.x * 256 + threadIdx.x;  // one float4 -> ushort4
    int total = Mpad * 128;                  // 512/4 per row
    if (t >= total) return;
    int row = t >> 7;
    ushort4 o;
    if (row < M) {
        float4 v = ((const float4*)x)[t];
        o.x = f2bf(v.x); o.y = f2bf(v.y); o.z = f2bf(v.z); o.w = f2bf(v.w);
    } else {
        o.x = o.y = o.z = o.w = 0;
    }
    ((ushort4*)Xb)[t] = o;
}

// W fp32 [K][N] -> Wt bf16 [Npad][K] (transposed, zero-padded rows)
__global__ void conv_wt_k(const float* __restrict__ W, ushort* __restrict__ Wt,
                          int kshift, int N, int total) {
    int t = blockIdx.x * 256 + threadIdx.x;
    if (t >= total) return;
    int K = 1 << kshift;
    int n = t >> kshift, k = t & (K - 1);
    Wt[t] = (n < N) ? f2bf(W[(size_t)k * N + n]) : (ushort)0;
}

// ---------------- CSR build ----------------

__global__ void count_indeg(const int* __restrict__ dst, int* __restrict__ indeg, int E) {
    int e = blockIdx.x * blockDim.x + threadIdx.x;
    if (e < E) atomicAdd(&indeg[dst[e]], 1);
}

// hierarchical scan: per-1024-chunk inclusive -> chunk totals -> combine
__global__ __launch_bounds__(1024) void scan1(const int* __restrict__ indeg,
                                              int* __restrict__ incl,   // rowptr as temp
                                              int* __restrict__ part, int n) {
    __shared__ int sm[1024];
    int i = blockIdx.x * 1024 + threadIdx.x;
    int v = (i < n) ? indeg[i] : 0;
    sm[threadIdx.x] = v;
    __syncthreads();
    #pragma unroll
    for (int off = 1; off < 1024; off <<= 1) {
        int t = (threadIdx.x >= (unsigned)off) ? sm[threadIdx.x - off] : 0;
        __syncthreads();
        sm[threadIdx.x] += t;
        __syncthreads();
    }
    if (i < n) incl[i] = sm[threadIdx.x];
    if (threadIdx.x == 1023) part[blockIdx.x] = sm[1023];
}

__global__ void scan2(int* __restrict__ part, int nb) {
    int t = threadIdx.x;  // 64
    int v = (t < nb) ? part[t] : 0;
    int orig = v;
    #pragma unroll
    for (int off = 1; off < 64; off <<= 1) {
        int u = __shfl_up(v, off, 64);
        if (t >= off) v += u;
    }
    if (t < nb) part[t] = v - orig;  // exclusive chunk offset
}

__global__ void scan3(const int* __restrict__ indeg, int* __restrict__ rowptr,
                      int* __restrict__ cursor, const int* __restrict__ part,
                      float* __restrict__ dinv, int n, int E) {
    int i = blockIdx.x * blockDim.x + threadIdx.x;
    if (i < n) {
        int excl = rowptr[i] - indeg[i] + part[i >> 10];
        rowptr[i] = excl;
        cursor[i] = excl;
        dinv[i] = rsqrtf((float)indeg[i] + 1.0f);  // +1 self-loop
    }
    if (i == 0) rowptr[n] = E;
}

__global__ void fill_csr(const int* __restrict__ src, const int* __restrict__ dst,
                         int* __restrict__ cursor, int* __restrict__ col, int E) {
    int e = blockIdx.x * blockDim.x + threadIdx.x;
    if (e < E) {
        int p = atomicAdd(&cursor[dst[e]], 1);
        col[p] = src[e];
    }
}

// ---------------- bf16 MFMA GEMM: C[m,n] = dinv[m] * sum_k A[m,k]*Bt[n,k] ----------------
// 128x128 tile, 256 threads = 4 waves (2x2), each wave 4x4 tiles of 16x16x32.

__global__ __launch_bounds__(256) void gemm_mfma(const ushort* __restrict__ A,
                                                 const ushort* __restrict__ Bt,
                                                 const float* __restrict__ dinv,
                                                 ushort* __restrict__ C,
                                                 int M, int Ncols, int K, int ldc) {
    __shared__ __align__(16) ushort As[128 * 32];
    __shared__ __align__(16) ushort Bs[128 * 32];
    int tid = threadIdx.x;
    int lane = tid & 63, w = tid >> 6;
    int wr = w >> 1, wc = w & 1;
    int bm = blockIdx.x * 128, bn = blockIdx.y * 128;

    float4_t acc[4][4];
    #pragma unroll
    for (int i = 0; i < 4; ++i)
        #pragma unroll
        for (int j = 0; j < 4; ++j) acc[i][j] = (float4_t)0.0f;

    // staging: thread t handles 16 B; rows 0..63 (issue 0) / 64..127 (issue 1)
    int r0 = tid >> 2;
    int kb = (tid & 3) * 8;  // element offset in 32-wide k-tile
    const ushort* ga0 = A + (size_t)(bm + r0) * K + kb;
    const ushort* ga1 = A + (size_t)(bm + r0 + 64) * K + kb;
    const ushort* gb0 = Bt + (size_t)(bn + r0) * K + kb;
    const ushort* gb1 = Bt + (size_t)(bn + r0 + 64) * K + kb;
    int ldsoff = r0 * 32 + kb;

    int arow = wr * 64 + (lane & 15);
    int brow = wc * 64 + (lane & 15);
    int quad = lane >> 4;

    for (int k0 = 0; k0 < K; k0 += 32) {
        short8_t a0 = *(const short8_t*)(ga0 + k0);
        short8_t a1 = *(const short8_t*)(ga1 + k0);
        short8_t b0 = *(const short8_t*)(gb0 + k0);
        short8_t b1 = *(const short8_t*)(gb1 + k0);
        __syncthreads();  // previous iter's readers done
        *(short8_t*)&As[ldsoff]        = a0;
        *(short8_t*)&As[ldsoff + 2048] = a1;
        *(short8_t*)&Bs[ldsoff]        = b0;
        *(short8_t*)&Bs[ldsoff + 2048] = b1;
        __syncthreads();
        short8_t aF[4], bF[4];
        #pragma unroll
        for (int i = 0; i < 4; ++i)
            aF[i] = *(const short8_t*)&As[(arow + i * 16) * 32 + quad * 8];
        #pragma unroll
        for (int j = 0; j < 4; ++j)
            bF[j] = *(const short8_t*)&Bs[(brow + j * 16) * 32 + quad * 8];
        #pragma unroll
        for (int i = 0; i < 4; ++i)
            #pragma unroll
            for (int j = 0; j < 4; ++j)
                acc[i][j] = __builtin_amdgcn_mfma_f32_16x16x32_bf16(aF[i], bF[j], acc[i][j], 0, 0, 0);
    }

    // C/D layout: col = lane&15, row = (lane>>4)*4 + reg
    int colb = bn + wc * 64 + (lane & 15);
    #pragma unroll
    for (int i = 0; i < 4; ++i) {
        int mb = bm + wr * 64 + i * 16 + quad * 4;
        #pragma unroll
        for (int r = 0; r < 4; ++r) {
            int m = mb + r;
            if (m >= M) continue;
            float s = dinv[m];
            #pragma unroll
            for (int j = 0; j < 4; ++j) {
                int n = colb + j * 16;
                if (n < Ncols) C[(size_t)m * ldc + n] = f2bf(acc[i][j][r] * s);
            }
        }
    }
}

// ---------------- aggregation: one wave per node, bf16 in/out, MLP-unrolled ----------------
// Edge ids are pre-loaded 64-at-a-time by the lanes (one coalesced load), then
// shfl-broadcast; gathers issue in groups of 8 (loads first, accumulate after)
// so ~8 row-gathers are in flight per wave instead of a serialized 1.

template <int F, bool RELU>
__global__ __launch_bounds__(256) void agg_bf(const ushort* __restrict__ g,
                                              const int* __restrict__ rowptr,
                                              const int* __restrict__ col,
                                              const float* __restrict__ dinv,
                                              const float* __restrict__ bias,
                                              ushort* __restrict__ out,
                                              int n, int npad) {
    constexpr int VPT = F / 64;
    int wid = (int)((blockIdx.x * blockDim.x + threadIdx.x) >> 6);
    int lane = threadIdx.x & 63;
    if (wid >= npad) return;
    int off = lane * VPT;
    ushort* orow = out + (size_t)wid * F + off;
    if (wid >= n) {  // zero padded tail rows (next GEMM reads them)
        #pragma unroll
        for (int j = 0; j < VPT; ++j) orow[j] = 0;
        return;
    }
    float acc[VPT];
    #pragma unroll
    for (int j = 0; j < VPT; ++j) acc[j] = 0.f;

    int e0 = rowptr[wid];
    int deg = rowptr[wid + 1] - e0;

    for (int base = 0; base < deg; base += 64) {
        int cnt = min(64, deg - base);
        int ec = (lane < cnt) ? col[e0 + base + lane] : 0;
        int j = 0;
        for (; j + 8 <= cnt; j += 8) {
            int s[8];
            #pragma unroll
            for (int u = 0; u < 8; ++u) s[u] = __shfl(ec, j + u);
            if constexpr (VPT == 4) {
                ushort4 v[8];
                #pragma unroll
                for (int u = 0; u < 8; ++u)
                    v[u] = *(const ushort4*)(g + (size_t)s[u] * F + off);
                #pragma unroll
                for (int u = 0; u < 8; ++u) {
                    acc[0] += bf2f(v[u].x); acc[1] += bf2f(v[u].y);
                    acc[2] += bf2f(v[u].z); acc[3] += bf2f(v[u].w);
                }
            } else if constexpr (VPT == 2) {
                ushort2 v[8];
                #pragma unroll
                for (int u = 0; u < 8; ++u)
                    v[u] = *(const ushort2*)(g + (size_t)s[u] * F + off);
                #pragma unroll
                for (int u = 0; u < 8; ++u) {
                    acc[0] += bf2f(v[u].x); acc[1] += bf2f(v[u].y);
                }
            } else {
                ushort v[8];
                #pragma unroll
                for (int u = 0; u < 8; ++u) v[u] = g[(size_t)s[u] * F + off];
                #pragma unroll
                for (int u = 0; u < 8; ++u) acc[0] += bf2f(v[u]);
            }
        }
        for (; j < cnt; ++j) {
            int s = __shfl(ec, j);
            const ushort* row = g + (size_t)s * F + off;
            if constexpr (VPT == 4) {
                ushort4 v = *(const ushort4*)row;
                acc[0] += bf2f(v.x); acc[1] += bf2f(v.y);
                acc[2] += bf2f(v.z); acc[3] += bf2f(v.w);
            } else if constexpr (VPT == 2) {
                ushort2 v = *(const ushort2*)row;
                acc[0] += bf2f(v.x); acc[1] += bf2f(v.y);
            } else {
                acc[0] += bf2f(row[0]);
            }
        }
    }

    const ushort* rowi = g + (size_t)wid * F + off;
    float di = dinv[wid];
    #pragma unroll
    for (int j = 0; j < VPT; ++j) {
        float v = di * (acc[j] + bf2f(rowi[j])) + bias[off + j];
        if (RELU) v = fmaxf(v, 0.f);
        orow[j] = f2bf(v);
    }
}

// ---------------- pooling + final linear ----------------

__global__ __launch_bounds__(256) void pool_sorted(const ushort* __restrict__ h,
                                                   const int* __restrict__ batch,
                                                   float* __restrict__ sums,
                                                   float* __restrict__ cnt, int n) {
    int wave = (int)((blockIdx.x * blockDim.x + threadIdx.x) >> 6);
    int lane = threadIdx.x & 63;
    int start = wave * 64;
    if (start >= n) return;
    int end = min(start + 64, n);
    float acc = 0.f;
    int cur = batch[start];
    int runlen = 0;
    for (int i = start; i < end; ++i) {
        int b = batch[i];
        if (b != cur) {
            atomicAdd(&sums[cur * 64 + lane], acc);
            if (lane == 0) atomicAdd(&cnt[cur], (float)runlen);
            acc = 0.f;
            runlen = 0;
            cur = b;
        }
        acc += bf2f(h[(size_t)i * 64 + lane]);
        runlen++;
    }
    atomicAdd(&sums[cur * 64 + lane], acc);
    if (lane == 0) atomicAdd(&cnt[cur], (float)runlen);
}

__global__ void final_lin(const float* __restrict__ sums, const float* __restrict__ cnt,
                          const float* __restrict__ Wl, const float* __restrict__ bl,
                          float* __restrict__ out) {
    int t = threadIdx.x;  // 128 threads: (graph, j)
    int g = t >> 1, j = t & 1;
    float c = fmaxf(cnt[g], 1.0f);
    float a = 0.f;
    #pragma unroll
    for (int k = 0; k < 64; ++k) a += sums[g * 64 + k] * Wl[k * 2 + j];
    out[t] = a / c + bl[j];
}

// ---------------- launch ----------------

extern "C" void kernel_launch(void* const* d_in, const int* in_sizes, int n_in,
                              void* d_out, int out_size, void* d_ws, size_t ws_size,
                              hipStream_t stream) {
    const float* x   = (const float*)d_in[0];
    const int*   ei  = (const int*)d_in[1];
    const int*   bat = (const int*)d_in[2];
    const float* W1  = (const float*)d_in[3];
    const float* b1  = (const float*)d_in[4];
    const float* W2  = (const float*)d_in[5];
    const float* b2  = (const float*)d_in[6];
    const float* W3  = (const float*)d_in[7];
    const float* b3  = (const float*)d_in[8];
    const float* Wl  = (const float*)d_in[9];
    const float* bl  = (const float*)d_in[10];
    float* out = (float*)d_out;

    const int N = in_sizes[0] / 512;
    const int E = in_sizes[1] / 2;
    const int Mpad = ((N + 127) / 128) * 128;   // 50048
    const int* src = ei;
    const int* dst = ei + E;

    char* w = (char*)d_ws;
    auto alloc = [&](size_t bytes) {
        char* p = w;
        w += (bytes + 255) & ~(size_t)255;
        return p;
    };
    ushort* Xb   = (ushort*)alloc((size_t)Mpad * 512 * 2);  // layer-1 A; H aliases it later
    ushort* G    = (ushort*)alloc((size_t)Mpad * 256 * 2);  // gemm output
    ushort* Wt1  = (ushort*)alloc(256 * 512 * 2);
    ushort* Wt2  = (ushort*)alloc(128 * 256 * 2);
    ushort* Wt3  = (ushort*)alloc(128 * 128 * 2);
    float* dinv  = (float*)alloc((size_t)N * 4);
    int* rowptr  = (int*)alloc((size_t)(N + 1) * 4);
    int* cursor  = (int*)alloc((size_t)N * 4);
    int* col     = (int*)alloc((size_t)E * 4);
    int* part    = (int*)alloc(256 * 4);
    size_t zbytes = (size_t)N * 4 + 64 * 64 * 4 + 64 * 4;  // indeg + sums + cnt
    int* indeg   = (int*)alloc(zbytes);
    float* sums  = (float*)(indeg + N);
    float* cnt   = sums + 64 * 64;
    ushort* H    = Xb;  // alias: Xb dead after gemm L1; H is Mpad*256 bf16 max

    hipMemsetAsync(indeg, 0, zbytes, stream);

    // converts
    conv_x_k<<<(Mpad * 128 + 255) / 256, 256, 0, stream>>>(x, Xb, N, Mpad);
    conv_wt_k<<<(256 * 512 + 255) / 256, 256, 0, stream>>>(W1, Wt1, 9, 256, 256 * 512);
    conv_wt_k<<<(128 * 256 + 255) / 256, 256, 0, stream>>>(W2, Wt2, 8, 128, 128 * 256);
    conv_wt_k<<<(128 * 128 + 255) / 256, 256, 0, stream>>>(W3, Wt3, 7, 64, 128 * 128);

    // CSR
    count_indeg<<<(E + 255) / 256, 256, 0, stream>>>(dst, indeg, E);
    int nb = (N + 1023) / 1024;
    scan1<<<nb, 1024, 0, stream>>>(indeg, rowptr, part, N);
    scan2<<<1, 64, 0, stream>>>(part, nb);
    scan3<<<(N + 255) / 256, 256, 0, stream>>>(indeg, rowptr, cursor, part, dinv, N, E);
    fill_csr<<<(E + 255) / 256, 256, 0, stream>>>(src, dst, cursor, col, E);

    int npad = Mpad;
    dim3 gemm_block(256);
    // layer 1: 512 -> 256
    gemm_mfma<<<dim3(Mpad / 128, 2), gemm_block, 0, stream>>>(Xb, Wt1, dinv, G, N, 256, 512, 256);
    agg_bf<256, true><<<npad / 4, 256, 0, stream>>>(G, rowptr, col, dinv, b1, H, N, npad);
    // layer 2: 256 -> 128
    gemm_mfma<<<dim3(Mpad / 128, 1), gemm_block, 0, stream>>>(H, Wt2, dinv, G, N, 128, 256, 128);
    agg_bf<128, true><<<npad / 4, 256, 0, stream>>>(G, rowptr, col, dinv, b2, H, N, npad);
    // layer 3: 128 -> 64 (Wt3 padded to 128 rows, store guarded n<64)
    gemm_mfma<<<dim3(Mpad / 128, 1), gemm_block, 0, stream>>>(H, Wt3, dinv, G, N, 64, 128, 64);
    agg_bf<64, false><<<npad / 4, 256, 0, stream>>>(G, rowptr, col, dinv, b3, H, N, npad);

    pool_sorted<<<(N + 255) / 256, 256, 0, stream>>>(H, bat, sums, cnt, N);
    final_lin<<<1, 128, 0, stream>>>(sums, cnt, Wl, bl, out);
}

// Round 5
// 492.838 us; speedup vs baseline: 2.4314x; 1.0099x over previous
//
#include <hip/hip_runtime.h>
#include <hip/hip_bf16.h>

// GCN: 3x gcn_conv + mean-pool + linear, bf16 MFMA pipeline.
// out[i] = dinv[i] * (sum_{e: dst=i} g[src_e] + g[i]) + b,  g = dinv .* (x @ W)

typedef __attribute__((ext_vector_type(8))) short short8_t;
typedef __attribute__((ext_vector_type(4))) float float4_t;

__device__ __forceinline__ unsigned short f2bf(float f) {
    unsigned int u = __float_as_uint(f);
    u += 0x7FFFu + ((u >> 16) & 1u);   // round-to-nearest-even
    return (unsigned short)(u >> 16);
}
__device__ __forceinline__ float bf2f(unsigned short h) {
    return __uint_as_float(((unsigned int)h) << 16);
}

// ---------------- weight convert ----------------

// W fp32 [K][N] -> Wt bf16 [Npad][K] (transposed, zero-padded rows)
__global__ void conv_wt_k(const float* __restrict__ W, ushort* __restrict__ Wt,
                          int kshift, int N, int total) {
    int t = blockIdx.x * 256 + threadIdx.x;
    if (t >= total) return;
    int K = 1 << kshift;
    int n = t >> kshift, k = t & (K - 1);
    Wt[t] = (n < N) ? f2bf(W[(size_t)k * N + n]) : (ushort)0;
}

// ---------------- CSR build ----------------

__global__ void count_indeg(const int* __restrict__ dst, int* __restrict__ indeg, int E) {
    int e = blockIdx.x * blockDim.x + threadIdx.x;
    if (e < E) atomicAdd(&indeg[dst[e]], 1);
}

// hierarchical scan: per-1024-chunk inclusive -> chunk totals -> combine
__global__ __launch_bounds__(1024) void scan1(const int* __restrict__ indeg,
                                              int* __restrict__ incl,   // rowptr as temp
                                              int* __restrict__ part, int n) {
    __shared__ int sm[1024];
    int i = blockIdx.x * 1024 + threadIdx.x;
    int v = (i < n) ? indeg[i] : 0;
    sm[threadIdx.x] = v;
    __syncthreads();
    #pragma unroll
    for (int off = 1; off < 1024; off <<= 1) {
        int t = (threadIdx.x >= (unsigned)off) ? sm[threadIdx.x - off] : 0;
        __syncthreads();
        sm[threadIdx.x] += t;
        __syncthreads();
    }
    if (i < n) incl[i] = sm[threadIdx.x];
    if (threadIdx.x == 1023) part[blockIdx.x] = sm[1023];
}

__global__ void scan2(int* __restrict__ part, int nb) {
    int t = threadIdx.x;  // 64
    int v = (t < nb) ? part[t] : 0;
    int orig = v;
    #pragma unroll
    for (int off = 1; off < 64; off <<= 1) {
        int u = __shfl_up(v, off, 64);
        if (t >= off) v += u;
    }
    if (t < nb) part[t] = v - orig;  // exclusive chunk offset
}

__global__ void scan3(const int* __restrict__ indeg, int* __restrict__ rowptr,
                      int* __restrict__ cursor, const int* __restrict__ part,
                      float* __restrict__ dinv, int n, int E) {
    int i = blockIdx.x * blockDim.x + threadIdx.x;
    if (i < n) {
        int excl = rowptr[i] - indeg[i] + part[i >> 10];
        rowptr[i] = excl;
        cursor[i] = excl;
        dinv[i] = rsqrtf((float)indeg[i] + 1.0f);  // +1 self-loop
    }
    if (i == 0) rowptr[n] = E;
}

__global__ void fill_csr(const int* __restrict__ src, const int* __restrict__ dst,
                         int* __restrict__ cursor, int* __restrict__ col, int E) {
    int e = blockIdx.x * blockDim.x + threadIdx.x;
    if (e < E) {
        int p = atomicAdd(&cursor[dst[e]], 1);
        col[p] = src[e];
    }
}

// ---------------- bf16 MFMA GEMM: C[m,n] = dinv[m] * sum_k A[m,k]*Bt[n,k] ----------------
// 128x128 tile, 256 threads = 4 waves (2x2), each wave 4x4 tiles of 16x16x32.
// AF32: A is fp32 and converted to bf16 during staging (fuses conv_x).

__device__ __forceinline__ short8_t load_cvt8(const float* __restrict__ A,
                                              size_t idx, bool ok) {
    short8_t r = (short8_t)0;
    if (ok) {
        float4 u = *(const float4*)(A + idx);
        float4 v = *(const float4*)(A + idx + 4);
        r[0] = (short)f2bf(u.x); r[1] = (short)f2bf(u.y);
        r[2] = (short)f2bf(u.z); r[3] = (short)f2bf(u.w);
        r[4] = (short)f2bf(v.x); r[5] = (short)f2bf(v.y);
        r[6] = (short)f2bf(v.z); r[7] = (short)f2bf(v.w);
    }
    return r;
}

template <bool AF32>
__global__ __launch_bounds__(256) void gemm_mfma(const void* __restrict__ Avp,
                                                 const ushort* __restrict__ Bt,
                                                 const float* __restrict__ dinv,
                                                 ushort* __restrict__ C,
                                                 int M, int Ncols, int K, int ldc) {
    __shared__ __align__(16) ushort As[128 * 32];
    __shared__ __align__(16) ushort Bs[128 * 32];
    int tid = threadIdx.x;
    int lane = tid & 63, w = tid >> 6;
    int wr = w >> 1, wc = w & 1;
    int bm = blockIdx.x * 128, bn = blockIdx.y * 128;

    float4_t acc[4][4];
    #pragma unroll
    for (int i = 0; i < 4; ++i)
        #pragma unroll
        for (int j = 0; j < 4; ++j) acc[i][j] = (float4_t)0.0f;

    // staging: thread t handles 16 B of LDS; rows 0..63 / 64..127
    int r0 = tid >> 2;
    int kb = (tid & 3) * 8;  // element offset in 32-wide k-tile
    int row0 = bm + r0, row1 = bm + r0 + 64;
    const ushort* A16 = (const ushort*)Avp;
    const float*  A32 = (const float*)Avp;
    size_t ra0 = (size_t)row0 * K + kb;
    size_t ra1 = (size_t)row1 * K + kb;
    const ushort* gb0 = Bt + (size_t)(bn + r0) * K + kb;
    const ushort* gb1 = Bt + (size_t)(bn + r0 + 64) * K + kb;
    int ldsoff = r0 * 32 + kb;

    int arow = wr * 64 + (lane & 15);
    int brow = wc * 64 + (lane & 15);
    int quad = lane >> 4;

    for (int k0 = 0; k0 < K; k0 += 32) {
        short8_t a0, a1;
        if constexpr (AF32) {
            a0 = load_cvt8(A32, ra0 + k0, row0 < M);
            a1 = load_cvt8(A32, ra1 + k0, row1 < M);
        } else {
            a0 = *(const short8_t*)(A16 + ra0 + k0);
            a1 = *(const short8_t*)(A16 + ra1 + k0);
        }
        short8_t b0 = *(const short8_t*)(gb0 + k0);
        short8_t b1 = *(const short8_t*)(gb1 + k0);
        __syncthreads();  // previous iter's readers done
        *(short8_t*)&As[ldsoff]        = a0;
        *(short8_t*)&As[ldsoff + 2048] = a1;
        *(short8_t*)&Bs[ldsoff]        = b0;
        *(short8_t*)&Bs[ldsoff + 2048] = b1;
        __syncthreads();
        short8_t aF[4], bF[4];
        #pragma unroll
        for (int i = 0; i < 4; ++i)
            aF[i] = *(const short8_t*)&As[(arow + i * 16) * 32 + quad * 8];
        #pragma unroll
        for (int j = 0; j < 4; ++j)
            bF[j] = *(const short8_t*)&Bs[(brow + j * 16) * 32 + quad * 8];
        #pragma unroll
        for (int i = 0; i < 4; ++i)
            #pragma unroll
            for (int j = 0; j < 4; ++j)
                acc[i][j] = __builtin_amdgcn_mfma_f32_16x16x32_bf16(aF[i], bF[j], acc[i][j], 0, 0, 0);
    }

    // C/D layout: col = lane&15, row = (lane>>4)*4 + reg
    int colb = bn + wc * 64 + (lane & 15);
    #pragma unroll
    for (int i = 0; i < 4; ++i) {
        int mb = bm + wr * 64 + i * 16 + quad * 4;
        #pragma unroll
        for (int r = 0; r < 4; ++r) {
            int m = mb + r;
            if (m >= M) continue;
            float s = dinv[m];
            #pragma unroll
            for (int j = 0; j < 4; ++j) {
                int n = colb + j * 16;
                if (n < Ncols) C[(size_t)m * ldc + n] = f2bf(acc[i][j][r] * s);
            }
        }
    }
}

// ---------------- aggregation: one wave per node, bf16 in/out, 16-deep MLP ----------------
// Edge ids pre-loaded 64-at-a-time (one coalesced load), shfl-broadcast; gathers
// issue in groups of 16 (then 4, then 1) - loads first, accumulate after - so up
// to 16 row-gathers are in flight per wave.

template <int F, bool RELU>
__global__ __launch_bounds__(256) void agg_bf(const ushort* __restrict__ g,
                                              const int* __restrict__ rowptr,
                                              const int* __restrict__ col,
                                              const float* __restrict__ dinv,
                                              const float* __restrict__ bias,
                                              ushort* __restrict__ out,
                                              int n, int npad) {
    constexpr int VPT = F / 64;
    int wid = (int)((blockIdx.x * blockDim.x + threadIdx.x) >> 6);
    int lane = threadIdx.x & 63;
    if (wid >= npad) return;
    int off = lane * VPT;
    ushort* orow = out + (size_t)wid * F + off;
    if (wid >= n) {  // zero padded tail rows (next GEMM reads them)
        #pragma unroll
        for (int j = 0; j < VPT; ++j) orow[j] = 0;
        return;
    }
    float acc[VPT];
    #pragma unroll
    for (int j = 0; j < VPT; ++j) acc[j] = 0.f;

    int e0 = rowptr[wid];
    int deg = rowptr[wid + 1] - e0;

    for (int base = 0; base < deg; base += 64) {
        int cnt = min(64, deg - base);
        int ec = (lane < cnt) ? col[e0 + base + lane] : 0;
        int j = 0;
        for (; j + 16 <= cnt; j += 16) {
            int s[16];
            #pragma unroll
            for (int u = 0; u < 16; ++u) s[u] = __shfl(ec, j + u);
            if constexpr (VPT == 4) {
                ushort4 v[16];
                #pragma unroll
                for (int u = 0; u < 16; ++u)
                    v[u] = *(const ushort4*)(g + (size_t)s[u] * F + off);
                #pragma unroll
                for (int u = 0; u < 16; ++u) {
                    acc[0] += bf2f(v[u].x); acc[1] += bf2f(v[u].y);
                    acc[2] += bf2f(v[u].z); acc[3] += bf2f(v[u].w);
                }
            } else if constexpr (VPT == 2) {
                ushort2 v[16];
                #pragma unroll
                for (int u = 0; u < 16; ++u)
                    v[u] = *(const ushort2*)(g + (size_t)s[u] * F + off);
                #pragma unroll
                for (int u = 0; u < 16; ++u) {
                    acc[0] += bf2f(v[u].x); acc[1] += bf2f(v[u].y);
                }
            } else {
                ushort v[16];
                #pragma unroll
                for (int u = 0; u < 16; ++u) v[u] = g[(size_t)s[u] * F + off];
                #pragma unroll
                for (int u = 0; u < 16; ++u) acc[0] += bf2f(v[u]);
            }
        }
        for (; j + 4 <= cnt; j += 4) {
            int s[4];
            #pragma unroll
            for (int u = 0; u < 4; ++u) s[u] = __shfl(ec, j + u);
            if constexpr (VPT == 4) {
                ushort4 v[4];
                #pragma unroll
                for (int u = 0; u < 4; ++u)
                    v[u] = *(const ushort4*)(g + (size_t)s[u] * F + off);
                #pragma unroll
                for (int u = 0; u < 4; ++u) {
                    acc[0] += bf2f(v[u].x); acc[1] += bf2f(v[u].y);
                    acc[2] += bf2f(v[u].z); acc[3] += bf2f(v[u].w);
                }
            } else if constexpr (VPT == 2) {
                ushort2 v[4];
                #pragma unroll
                for (int u = 0; u < 4; ++u)
                    v[u] = *(const ushort2*)(g + (size_t)s[u] * F + off);
                #pragma unroll
                for (int u = 0; u < 4; ++u) {
                    acc[0] += bf2f(v[u].x); acc[1] += bf2f(v[u].y);
                }
            } else {
                ushort v[4];
                #pragma unroll
                for (int u = 0; u < 4; ++u) v[u] = g[(size_t)s[u] * F + off];
                #pragma unroll
                for (int u = 0; u < 4; ++u) acc[0] += bf2f(v[u]);
            }
        }
        for (; j < cnt; ++j) {
            int s = __shfl(ec, j);
            const ushort* row = g + (size_t)s * F + off;
            if constexpr (VPT == 4) {
                ushort4 v = *(const ushort4*)row;
                acc[0] += bf2f(v.x); acc[1] += bf2f(v.y);
                acc[2] += bf2f(v.z); acc[3] += bf2f(v.w);
            } else if constexpr (VPT == 2) {
                ushort2 v = *(const ushort2*)row;
                acc[0] += bf2f(v.x); acc[1] += bf2f(v.y);
            } else {
                acc[0] += bf2f(row[0]);
            }
        }
    }

    const ushort* rowi = g + (size_t)wid * F + off;
    float di = dinv[wid];
    #pragma unroll
    for (int j = 0; j < VPT; ++j) {
        float v = di * (acc[j] + bf2f(rowi[j])) + bias[off + j];
        if (RELU) v = fmaxf(v, 0.f);
        orow[j] = f2bf(v);
    }
}

// ---------------- pooling + final linear ----------------

__global__ __launch_bounds__(256) void pool_sorted(const ushort* __restrict__ h,
                                                   const int* __restrict__ batch,
                                                   float* __restrict__ sums,
                                                   float* __restrict__ cnt, int n) {
    int wave = (int)((blockIdx.x * blockDim.x + threadIdx.x) >> 6);
    int lane = threadIdx.x & 63;
    int start = wave * 64;
    if (start >= n) return;
    int end = min(start + 64, n);
    float acc = 0.f;
    int cur = batch[start];
    int runlen = 0;
    for (int i = start; i < end; ++i) {
        int b = batch[i];
        if (b != cur) {
            atomicAdd(&sums[cur * 64 + lane], acc);
            if (lane == 0) atomicAdd(&cnt[cur], (float)runlen);
            acc = 0.f;
            runlen = 0;
            cur = b;
        }
        acc += bf2f(h[(size_t)i * 64 + lane]);
        runlen++;
    }
    atomicAdd(&sums[cur * 64 + lane], acc);
    if (lane == 0) atomicAdd(&cnt[cur], (float)runlen);
}

__global__ void final_lin(const float* __restrict__ sums, const float* __restrict__ cnt,
                          const float* __restrict__ Wl, const float* __restrict__ bl,
                          float* __restrict__ out) {
    int t = threadIdx.x;  // 128 threads: (graph, j)
    int g = t >> 1, j = t & 1;
    float c = fmaxf(cnt[g], 1.0f);
    float a = 0.f;
    #pragma unroll
    for (int k = 0; k < 64; ++k) a += sums[g * 64 + k] * Wl[k * 2 + j];
    out[t] = a / c + bl[j];
}

// ---------------- launch ----------------

extern "C" void kernel_launch(void* const* d_in, const int* in_sizes, int n_in,
                              void* d_out, int out_size, void* d_ws, size_t ws_size,
                              hipStream_t stream) {
    const float* x   = (const float*)d_in[0];
    const int*   ei  = (const int*)d_in[1];
    const int*   bat = (const int*)d_in[2];
    const float* W1  = (const float*)d_in[3];
    const float* b1  = (const float*)d_in[4];
    const float* W2  = (const float*)d_in[5];
    const float* b2  = (const float*)d_in[6];
    const float* W3  = (const float*)d_in[7];
    const float* b3  = (const float*)d_in[8];
    const float* Wl  = (const float*)d_in[9];
    const float* bl  = (const float*)d_in[10];
    float* out = (float*)d_out;

    const int N = in_sizes[0] / 512;
    const int E = in_sizes[1] / 2;
    const int Mpad = ((N + 127) / 128) * 128;   // 50048
    const int* src = ei;
    const int* dst = ei + E;

    char* w = (char*)d_ws;
    auto alloc = [&](size_t bytes) {
        char* p = w;
        w += (bytes + 255) & ~(size_t)255;
        return p;
    };
    ushort* G    = (ushort*)alloc((size_t)Mpad * 256 * 2);  // gemm output
    ushort* H    = (ushort*)alloc((size_t)Mpad * 256 * 2);  // agg output
    ushort* Wt1  = (ushort*)alloc(256 * 512 * 2);
    ushort* Wt2  = (ushort*)alloc(128 * 256 * 2);
    ushort* Wt3  = (ushort*)alloc(128 * 128 * 2);
    float* dinv  = (float*)alloc((size_t)N * 4);
    int* rowptr  = (int*)alloc((size_t)(N + 1) * 4);
    int* cursor  = (int*)alloc((size_t)N * 4);
    int* col     = (int*)alloc((size_t)E * 4);
    int* part    = (int*)alloc(256 * 4);
    size_t zbytes = (size_t)N * 4 + 64 * 64 * 4 + 64 * 4;  // indeg + sums + cnt
    int* indeg   = (int*)alloc(zbytes);
    float* sums  = (float*)(indeg + N);
    float* cnt   = sums + 64 * 64;

    hipMemsetAsync(indeg, 0, zbytes, stream);

    // weight converts (x conversion is fused into gemm L1)
    conv_wt_k<<<(256 * 512 + 255) / 256, 256, 0, stream>>>(W1, Wt1, 9, 256, 256 * 512);
    conv_wt_k<<<(128 * 256 + 255) / 256, 256, 0, stream>>>(W2, Wt2, 8, 128, 128 * 256);
    conv_wt_k<<<(128 * 128 + 255) / 256, 256, 0, stream>>>(W3, Wt3, 7, 64, 128 * 128);

    // CSR
    count_indeg<<<(E + 255) / 256, 256, 0, stream>>>(dst, indeg, E);
    int nb = (N + 1023) / 1024;
    scan1<<<nb, 1024, 0, stream>>>(indeg, rowptr, part, N);
    scan2<<<1, 64, 0, stream>>>(part, nb);
    scan3<<<(N + 255) / 256, 256, 0, stream>>>(indeg, rowptr, cursor, part, dinv, N, E);
    fill_csr<<<(E + 255) / 256, 256, 0, stream>>>(src, dst, cursor, col, E);

    int npad = Mpad;
    // layer 1: 512 -> 256 (A = x fp32, converted in staging)
    gemm_mfma<true><<<dim3(Mpad / 128, 2), 256, 0, stream>>>(x, Wt1, dinv, G, N, 256, 512, 256);
    agg_bf<256, true><<<npad / 4, 256, 0, stream>>>(G, rowptr, col, dinv, b1, H, N, npad);
    // layer 2: 256 -> 128
    gemm_mfma<false><<<dim3(Mpad / 128, 1), 256, 0, stream>>>(H, Wt2, dinv, G, N, 128, 256, 128);
    agg_bf<128, true><<<npad / 4, 256, 0, stream>>>(G, rowptr, col, dinv, b2, H, N, npad);
    // layer 3: 128 -> 64 (Wt3 padded to 128 rows, store guarded n<64)
    gemm_mfma<false><<<dim3(Mpad / 128, 1), 256, 0, stream>>>(H, Wt3, dinv, G, N, 64, 128, 64);
    agg_bf<64, false><<<npad / 4, 256, 0, stream>>>(G, rowptr, col, dinv, b3, H, N, npad);

    pool_sorted<<<(N + 255) / 256, 256, 0, stream>>>(H, bat, sums, cnt, N);
    final_lin<<<1, 128, 0, stream>>>(sums, cnt, Wl, bl, out);
}